// Round 14
// baseline (209.237 us; speedup 1.0000x reference)
//
#include <hip/hip_runtime.h>
#include <hip/hip_fp16.h>
#include <math.h>

#define HH 512
#define WW 512
#define BB 4
#define NPIX (BB * HH * WW)

#define HS 4                  // core rows per wave
#define CORE 124              // core cols per wave (2 px/lane, lanes 1..62)
#define NSX 5                 // 5*124 = 620 >= 512
#define NBAND (HH / HS)       // 128
#define NWAVES (NSX * NBAND * BB)   // 2560
#define NBLK (NWAVES / 4)           // 640

constexpr float TAUf   = 0.01f;
constexpr float RHOf   = 1.99f;
constexpr float SIGMAf = (float)(1.0 / 0.01 / 72.0);
constexpr float INV1PT = (float)(1.0 / 1.01);

struct v2 { float x, y; };
__device__ __forceinline__ v2 mkv2(float a, float b) { v2 r; r.x = a; r.y = b; return r; }
__device__ __forceinline__ v2 operator+(v2 a, v2 b) { return mkv2(a.x + b.x, a.y + b.y); }
__device__ __forceinline__ v2 operator-(v2 a, v2 b) { return mkv2(a.x - b.x, a.y - b.y); }
__device__ __forceinline__ v2 operator*(v2 a, v2 b) { return mkv2(a.x * b.x, a.y * b.y); }
__device__ __forceinline__ v2 operator*(float a, v2 b) { return mkv2(a * b.x, a * b.y); }

__device__ __forceinline__ float SD(float v)  { return __shfl_down(v, 1, 64); }
__device__ __forceinline__ float SUp(float v) { return __shfl_up(v, 1, 64); }
// paired-column neighbor access: one shuffle per pair
__device__ __forceinline__ v2 RIGHT(v2 a) { return mkv2(a.y, SD(a.x)); }   // value at col+1
__device__ __forceinline__ v2 LEFT(v2 a)  { return mkv2(SUp(a.y), a.x); }  // value at col-1

__device__ __forceinline__ v2 u2v(unsigned u) {
    __half2 h = *reinterpret_cast<__half2*>(&u);
    return mkv2(__low2float(h), __high2float(h));
}
__device__ __forceinline__ unsigned v2u(float a, float b) {
    __half2 h = __floats2half2_rn(a, b);
    return *reinterpret_cast<unsigned*>(&h);
}

// R8 skeleton (10 launches, chained register rings) with 2 columns per lane.
// MODE: 0 = iter0 (x=y, r=0, u=0); 1 = mid; 2 = last (x-only, f32 out)
template <int MODE>
__global__ __launch_bounds__(256, 3) void sweep(
    const float* __restrict__ y, const int* __restrict__ ths_p,
    const __half* __restrict__ x2_in, const __half* __restrict__ r2_in,
    const __half* __restrict__ u_in,
    __half* __restrict__ x2_out, __half* __restrict__ r2_out,
    __half* __restrict__ u_out, float* __restrict__ xout)
{
    const int tid  = threadIdx.x;
    const int lane = tid & 63;
    const int wid  = blockIdx.x * 4 + (tid >> 6);
    const int sx   = wid % NSX;
    const int t2   = wid / NSX;
    const int band = t2 & (NBAND - 1);
    const int b    = t2 / NBAND;
    const int R0   = band * HS;
    const int c    = sx * CORE - 2 + 2 * lane;   // even; pair = cols (c, c+1)
    const int boff = b * (HH * WW);
    const bool wok = ((unsigned)c) < (unsigned)WW;     // pair fully in image
    const bool cok = (lane >= 1) && (lane <= 62) && (((unsigned)c) < (unsigned)WW);
    const int cx = c, cy = c + 1;
    const v2 mA = mkv2((cx >= 1 && cx < WW) ? 1.f : 0.f,
                       (cy >= 1 && cy < WW) ? 1.f : 0.f);
    const v2 mB = mkv2((cx >= 0 && cx < WW - 1) ? 1.f : 0.f,
                       (cy >= 0 && cy < WW - 1) ? 1.f : 0.f);
    const v2 zz = mkv2(0.f, 0.f);

    const float ths     = (float)ths_p[0];
    const float inv_tl1 = 1.0f / (TAUf * (ths * 0.1f));
    const float inv_l2  = 1.0f / (ths * 0.15f);

    // register rings
    v2 u0[4], u1[4], u2[4], u3[4];
    v2 i0r[2], i1r[2];
    v2 sr[4], t0r[4], t1r[4];
    #pragma unroll
    for (int q = 0; q < 4; ++q) { u0[q]=u1[q]=u2[q]=u3[q]=zz; sr[q]=t0r[q]=t1r[q]=zz; }
    i0r[0]=i0r[1]=i1r[0]=i1r[1]=zz;

    auto uload = [&](int row) -> uint4 {
        uint4 z; z.x = z.y = z.z = z.w = 0u;
        if (((unsigned)row) < (unsigned)HH && wok)
            z = *(const uint4*)(u_in + 4 * (size_t)(boff + row * WW + c));
        return z;
    };
    auto unpk = [&](int sl, uint4 raw) {
        v2 a = u2v(raw.x), bb = u2v(raw.y), cc = u2v(raw.z), dd = u2v(raw.w);
        u0[sl] = mkv2(a.x, cc.x); u1[sl] = mkv2(a.y, cc.y);
        u2[sl] = mkv2(bb.x, dd.x); u3[sl] = mkv2(bb.y, dd.y);
    };
    // i(rr): islot; cs = u slot of row rr, ds = row rr+1, us = row rr-1
    auto compI = [&](int rr, int isl, int cs, int ds, int us) {
        if (((unsigned)rr) < (unsigned)HH) {
            float hD = (rr < HH - 1) ? 1.f : 0.f;
            v2 u1c = u1[cs], u2c = u2[cs];
            i0r[isl] = u0[cs] - u0[ds] - RIGHT(u1c) + mA * u1c;
            i1r[isl] = u2c - RIGHT(u2c) - hD * u3[cs] + u3[us];
        } else { i0r[isl] = zz; i1r[isl] = zz; }
    };

    if (MODE == 2) {
        // ---- last iter: only x output (f32) ----
        unpk(2, uload(R0 - 2));
        unpk(3, uload(R0 - 1));
        unpk(0, uload(R0));
        compI(R0 - 1, 1, 3, 0, 2);
        uint4 pu = uload(R0 + 1);
        v2 py, px2;
        {
            int idx = boff + R0 * WW + c;
            py  = wok ? *(const v2*)(y + idx) : zz;
            px2 = wok ? u2v(*(const unsigned*)(x2_in + idx)) : zz;
        }
        #pragma unroll
        for (int k = 0; k < HS; ++k) {
            const int rr = R0 + k;
            unpk((k + 1) & 3, pu);
            uint4 nu; nu.x = nu.y = nu.z = nu.w = 0u;
            if (k < HS - 1) nu = uload(rr + 2);
            v2 yv = py, x2v = px2;
            if (k < HS - 1) {
                int idx = boff + (rr + 1) * WW + c;
                py  = wok ? *(const v2*)(y + idx) : zz;
                px2 = wok ? u2v(*(const unsigned*)(x2_in + idx)) : zz;
            }
            compI(rr, k & 1, k & 3, (k + 1) & 3, (k + 3) & 3);
            float hD = (rr < HH - 1) ? 1.f : 0.f;
            v2 i0c = i0r[k & 1], i1c = i1r[k & 1], i1u = i1r[(k + 1) & 1];
            v2 na = TAUf * (mA * LEFT(i0c) - mB * i0c + i1u - hD * i1c);
            v2 x = INV1PT * (x2v - na + TAUf * yv);
            v2 out = x2v + RHOf * (x - x2v);
            if (cok) *(v2*)(xout + boff + rr * WW + c) = out;
            pu = nu;
        }
        return;
    }

    // s,t(rr); relax writes on core rows
    auto compS = [&](int rr, int ss_, int isc, int isp,
                     v2 yv, v2 x2v, v2 r20v, v2 r21v, bool coreRow) {
        if (((unsigned)rr) < (unsigned)HH) {
            if (MODE == 0) {
                sr[ss_] = yv; t0r[ss_] = zz; t1r[ss_] = zz;
                if (coreRow && cok) {
                    int idx = boff + rr * WW + c;
                    *(unsigned*)(x2_out + idx) = v2u(yv.x, yv.y);
                    uint2 st; st.x = v2u(0.f, 0.f); st.y = v2u(0.f, 0.f);
                    *(uint2*)(r2_out + 2 * (size_t)idx) = st;
                }
            } else {
                float hD = (rr < HH - 1) ? 1.f : 0.f;
                v2 i0c = i0r[isc], i1c = i1r[isc], i1u = i1r[isp];
                v2 na = TAUf * (mA * LEFT(i0c) - mB * i0c + i1u - hD * i1c);
                v2 x = INV1PT * (x2v - na + TAUf * yv);
                v2 rr0 = r20v + TAUf * i0c;
                v2 rr1 = r21v + TAUf * i1c;
                float mgx = sqrtf(rr0.x * rr0.x + rr1.x * rr1.x) * inv_tl1;
                float mgy = sqrtf(rr0.y * rr0.y + rr1.y * rr1.y) * inv_tl1;
                v2 ri = mkv2(1.f / fmaxf(mgx, 1.f), 1.f / fmaxf(mgy, 1.f));
                v2 r0 = rr0 - rr0 * ri;
                v2 r1 = rr1 - rr1 * ri;
                sr[ss_]  = 2.f * x  - x2v;
                t0r[ss_] = 2.f * r0 - r20v;
                t1r[ss_] = 2.f * r1 - r21v;
                if (coreRow && cok) {
                    int idx = boff + rr * WW + c;
                    v2 x2n = x2v + RHOf * (x - x2v);
                    v2 r0n = r20v + RHOf * (r0 - r20v);
                    v2 r1n = r21v + RHOf * (r1 - r21v);
                    *(unsigned*)(x2_out + idx) = v2u(x2n.x, x2n.y);
                    uint2 st; st.x = v2u(r0n.x, r1n.x); st.y = v2u(r0n.y, r1n.y);
                    *(uint2*)(r2_out + 2 * (size_t)idx) = st;
                }
            }
        } else { sr[ss_] = zz; t0r[ss_] = zz; t1r[ss_] = zz; }
    };

    // u'(ro) dual update -> global
    auto compU = [&](int ro, int sc_, int sd_, int suu, int sdd_, int uslot) {
        float hD  = (ro < HH - 1) ? 1.f : 0.f;
        float hD1 = (ro + 1 < HH - 1) ? 1.f : 0.f;
        v2 sc = sr[sc_], sd = sr[sd_], su = sr[suu], s2 = sr[sdd_];
        v2 t0c = t0r[sc_], t0u = t0r[suu];
        v2 t1c = t1r[sc_], t1d = t1r[sd_];
        v2 sc_l = LEFT(sc), sd_l = LEFT(sd);
        v2 t0c_l = LEFT(t0c), t1c_l = LEFT(t1c);
        v2 v0c = mB * (RIGHT(sc) - sc) - t0c;
        v2 v1c = hD * (sd - sc) - t1c;
        v2 v0u = mB * (RIGHT(su) - su) - t0u;
        v2 v0l = (sc - sc_l) - t0c_l;
        v2 v1l = hD * (sd_l - sc_l) - t1c_l;
        v2 v1d = hD1 * (s2 - sd) - t1d;
        v2 G0 = v0c - v0u;
        v2 G1 = mA * (v0c - v0l);
        v2 G2 = v1c - mA * v1l;
        v2 G3 = hD * (v1d - v1c);
        v2 a0, a1, a2, a3;
        if (MODE == 0) { a0 = a1 = a2 = a3 = zz; }
        else { a0 = u0[uslot]; a1 = u1[uslot]; a2 = u2[uslot]; a3 = u3[uslot]; }
        v2 b0 = a0 + SIGMAf * G0;
        v2 b1 = a1 + SIGMAf * G1;
        v2 b2 = a2 + SIGMAf * G2;
        v2 b3 = a3 + SIGMAf * G3;
        float mgx = sqrtf(b0.x * b0.x + b1.x * b1.x + b2.x * b2.x + b3.x * b3.x) * inv_l2;
        float mgy = sqrtf(b0.y * b0.y + b1.y * b1.y + b2.y * b2.y + b3.y * b3.y) * inv_l2;
        v2 ui = mkv2(1.f / fmaxf(mgx, 1.f), 1.f / fmaxf(mgy, 1.f));
        if (cok) {
            int idx = boff + ro * WW + c;
            v2 n0 = a0 + RHOf * (b0 * ui - a0);
            v2 n1 = a1 + RHOf * (b1 * ui - a1);
            v2 n2 = a2 + RHOf * (b2 * ui - a2);
            v2 n3 = a3 + RHOf * (b3 * ui - a3);
            uint4 st;
            st.x = v2u(n0.x, n1.x); st.y = v2u(n2.x, n3.x);
            st.z = v2u(n0.y, n1.y); st.w = v2u(n2.y, n3.y);
            *(uint4*)(u_out + 4 * (size_t)idx) = st;
        }
    };

    // ---- prologue ----
    uint4 pu; pu.x = pu.y = pu.z = pu.w = 0u;
    v2 py = zz, px2 = zz, pr0 = zz, pr1 = zz;
    if (MODE != 0) {
        unpk(1, uload(R0 - 3));
        unpk(2, uload(R0 - 2));
        unpk(3, uload(R0 - 1));
        compI(R0 - 2, 0, 2, 3, 1);
        pu = uload(R0);
    }
    {
        int row = R0 - 1; bool ok = (((unsigned)row) < (unsigned)HH) && wok;
        int idx = boff + row * WW + c;
        py = ok ? *(const v2*)(y + idx) : zz;
        if (MODE != 0) {
            px2 = ok ? u2v(*(const unsigned*)(x2_in + idx)) : zz;
            if (ok) {
                uint2 rv = *(const uint2*)(r2_in + 2 * (size_t)idx);
                v2 p0 = u2v(rv.x), p1 = u2v(rv.y);
                pr0 = mkv2(p0.x, p1.x); pr1 = mkv2(p0.y, p1.y);
            }
        }
    }

    // ---- main pipeline: rr = R0-1 .. R0+HS+1 ----
    #pragma unroll
    for (int k = 0; k < HS + 3; ++k) {
        const int rr = R0 - 1 + k;
        uint4 nu; nu.x = nu.y = nu.z = nu.w = 0u;
        if (MODE != 0) { unpk(k & 3, pu); if (k < HS + 2) nu = uload(rr + 2); }
        v2 yv = py, x2v = px2, r20v = pr0, r21v = pr1;
        if (k < HS + 2) {
            int row = rr + 1; bool ok = (((unsigned)row) < (unsigned)HH) && wok;
            int idx = boff + row * WW + c;
            py = ok ? *(const v2*)(y + idx) : zz;
            if (MODE != 0) {
                px2 = ok ? u2v(*(const unsigned*)(x2_in + idx)) : zz;
                if (ok) {
                    uint2 rv = *(const uint2*)(r2_in + 2 * (size_t)idx);
                    v2 p0 = u2v(rv.x), p1 = u2v(rv.y);
                    pr0 = mkv2(p0.x, p1.x); pr1 = mkv2(p0.y, p1.y);
                } else { pr0 = zz; pr1 = zz; }
            }
        }
        if (MODE != 0) compI(rr, (k + 1) & 1, (k + 3) & 3, k & 3, (k + 2) & 3);
        compS(rr, (k + 3) & 3, (k + 1) & 1, k & 1, yv, x2v, r20v, r21v,
              (k >= 1 && k <= HS));
        if (k >= 3) compU(R0 - 3 + k, (k + 1) & 3, (k + 2) & 3, k & 3, (k + 3) & 3,
                          (k + 1) & 3);
        if (MODE != 0) pu = nu;
    }
}

extern "C" void kernel_launch(void* const* d_in, const int* in_sizes, int n_in,
                              void* d_out, int out_size, void* d_ws, size_t ws_size,
                              hipStream_t stream)
{
    const float* y   = (const float*)d_in[0];
    const int*   ths = (const int*)d_in[1];
    __half* ws = (__half*)d_ws;

    __half* Ax2 = ws;
    __half* Ar2 = ws + (size_t)NPIX;
    __half* Au  = ws + (size_t)3 * NPIX;
    __half* Bx2 = ws + (size_t)7 * NPIX;
    __half* Br2 = ws + (size_t)8 * NPIX;
    __half* Bu  = ws + (size_t)10 * NPIX;
    float*  xout = (float*)d_out;

    dim3 block(256);
    dim3 grid(NBLK);

    // iter 0 (analytic) -> B
    sweep<0><<<grid, block, 0, stream>>>(y, ths, Ax2, Ar2, Au, Bx2, Br2, Bu, nullptr);
    // iters 1..8 alternate
    __half *ix2 = Bx2, *ir2 = Br2, *iu = Bu;
    __half *ox2 = Ax2, *or2 = Ar2, *ou = Au;
    for (int it = 1; it <= 8; ++it) {
        sweep<1><<<grid, block, 0, stream>>>(y, ths, ix2, ir2, iu, ox2, or2, ou, nullptr);
        __half* t;
        t = ix2; ix2 = ox2; ox2 = t;
        t = ir2; ir2 = or2; or2 = t;
        t = iu;  iu  = ou;  ou  = t;
    }
    // iter 9: x only -> d_out
    sweep<2><<<grid, block, 0, stream>>>(y, ths, ix2, ir2, iu, nullptr, nullptr, nullptr, xout);
}